// Round 1
// baseline (108.141 us; speedup 1.0000x reference)
//
#include <hip/hip_runtime.h>

#define SAMPLE_S 5

__global__ void init_out_kernel(float* out) {
    if (threadIdx.x == 0) {
        out[0] = 0.0f;
        out[1] = 0.0f;
    }
}

__device__ __forceinline__ float f4_get(const float4& v, int c) {
    switch (c) {
        case 0: return v.x;
        case 1: return v.y;
        case 2: return v.z;
        default: return v.w;
    }
}

// Process one (split n, row i): 5 o-values, 5 l-values.
// loss += relu(margin)*S  (diagonal)  + 2 * sum_{j<k} relu(margin - (oj-ok)*(lj-lk))
// cnt  += (argmax(o_row) == argmax(l_row))   [first-max tie semantics]
__device__ __forceinline__ void process_row(const float ox[SAMPLE_S], const float lx[SAMPLE_S],
                                            float margin, float& loss, float& cnt) {
    int po = 0, pl = 0;
    float mo = ox[0], ml = lx[0];
#pragma unroll
    for (int j = 1; j < SAMPLE_S; ++j) {
        bool bo = ox[j] > mo;   // strict > keeps FIRST max (jnp.argmax semantics)
        mo = bo ? ox[j] : mo;
        po = bo ? j : po;
        bool bl = lx[j] > ml;
        ml = bl ? lx[j] : ml;
        pl = bl ? j : pl;
    }
    if (po == pl) cnt += 1.0f;

    loss += fmaxf(margin, 0.0f) * (float)SAMPLE_S;  // j==k terms: relu(margin - 0)
#pragma unroll
    for (int j = 0; j < SAMPLE_S; ++j) {
#pragma unroll
        for (int k = j + 1; k < SAMPLE_S; ++k) {
            float t = margin - (ox[j] - ox[k]) * (lx[j] - lx[k]);
            loss += 2.0f * fmaxf(t, 0.0f);   // (j,k) and (k,j) are equal
        }
    }
}

__global__ __launch_bounds__(256) void pml_main_kernel(
        const float* __restrict__ o, const float* __restrict__ l,
        const int* __restrict__ margin_p, float* __restrict__ out, int N) {
    const float margin = (float)(*margin_p);
    const long long t  = (long long)blockIdx.x * 256 + threadIdx.x;
    const long long n4 = t * 4;

    float loss = 0.0f, cnt = 0.0f;

    if (n4 + 3 < (long long)N) {
        // Vectorized path: 4 consecutive splits per thread, float4 (16B/lane) coalesced loads.
#pragma unroll
        for (int i = 0; i < SAMPLE_S; ++i) {
            float4 ov[SAMPLE_S], lv[SAMPLE_S];
#pragma unroll
            for (int j = 0; j < SAMPLE_S; ++j) {
                const long long base = (long long)(i * SAMPLE_S + j) * N + n4;
                ov[j] = *reinterpret_cast<const float4*>(o + base);
                lv[j] = *reinterpret_cast<const float4*>(l + base);
            }
#pragma unroll
            for (int c = 0; c < 4; ++c) {
                float ox[SAMPLE_S], lx[SAMPLE_S];
#pragma unroll
                for (int j = 0; j < SAMPLE_S; ++j) {
                    ox[j] = f4_get(ov[j], c);
                    lx[j] = f4_get(lv[j], c);
                }
                process_row(ox, lx, margin, loss, cnt);
            }
        }
    } else if (n4 < (long long)N) {
        // Scalar tail (unused when N % 4 == 0, kept for generality).
        for (long long n = n4; n < (long long)N; ++n) {
#pragma unroll
            for (int i = 0; i < SAMPLE_S; ++i) {
                float ox[SAMPLE_S], lx[SAMPLE_S];
#pragma unroll
                for (int j = 0; j < SAMPLE_S; ++j) {
                    const long long idx = (long long)(i * SAMPLE_S + j) * N + n;
                    ox[j] = o[idx];
                    lx[j] = l[idx];
                }
                process_row(ox, lx, margin, loss, cnt);
            }
        }
    }

    // Wave-64 shuffle reduction, then cross-wave via LDS, one atomic pair per block.
#pragma unroll
    for (int off = 32; off > 0; off >>= 1) {
        loss += __shfl_down(loss, off, 64);
        cnt  += __shfl_down(cnt,  off, 64);
    }
    __shared__ float sl[4], sc[4];
    const int wave = threadIdx.x >> 6;
    const int lane = threadIdx.x & 63;
    if (lane == 0) { sl[wave] = loss; sc[wave] = cnt; }
    __syncthreads();
    if (threadIdx.x == 0) {
        float L = sl[0] + sl[1] + sl[2] + sl[3];
        float C = sc[0] + sc[1] + sc[2] + sc[3];
        atomicAdd(&out[0], L);
        atomicAdd(&out[1], C);
    }
}

extern "C" void kernel_launch(void* const* d_in, const int* in_sizes, int n_in,
                              void* d_out, int out_size, void* d_ws, size_t ws_size,
                              hipStream_t stream) {
    const float* o      = (const float*)d_in[0];
    const float* l      = (const float*)d_in[1];
    const int*   margin = (const int*)d_in[2];
    float*       out    = (float*)d_out;

    const int N = in_sizes[0] / (SAMPLE_S * SAMPLE_S);

    hipLaunchKernelGGL(init_out_kernel, dim3(1), dim3(64), 0, stream, out);

    const long long threads = ((long long)N + 3) / 4;
    const int blocks = (int)((threads + 255) / 256);
    hipLaunchKernelGGL(pml_main_kernel, dim3(blocks), dim3(256), 0, stream,
                       o, l, margin, out, N);
}